// Round 3
// baseline (545.704 us; speedup 1.0000x reference)
//
#include <hip/hip_runtime.h>

#define BB 64
#define CC 1024
#define QQ 128
#define HH 512

typedef short bf16x8 __attribute__((ext_vector_type(8)));
typedef float f32x4 __attribute__((ext_vector_type(4)));

#define GLD16(g, l)                                                            \
    __builtin_amdgcn_global_load_lds(                                          \
        (const __attribute__((address_space(1))) unsigned int*)(g),            \
        (__attribute__((address_space(3))) unsigned int*)(l), 16, 0, 0)

__device__ __forceinline__ unsigned short f2bf(float f) {
    unsigned u = __float_as_uint(f);
    u += 0x7FFF + ((u >> 16) & 1);          // RNE
    return (unsigned short)(u >> 16);
}
__device__ __forceinline__ unsigned pk2(float lo, float hi) {
    return (unsigned)f2bf(lo) | ((unsigned)f2bf(hi) << 16);
}

// ---------------- K0: sub0[b,q] = dot(xq[b,q,:], W0); also zero colsum ----
__global__ __launch_bounds__(256) void k_sub0(const float* __restrict__ xq,
                                              const float* __restrict__ w0,
                                              float* __restrict__ sub0,
                                              float* __restrict__ colsum) {
    if (blockIdx.x < 32) colsum[blockIdx.x * 256 + threadIdx.x] = 0.0f;
    int wave = threadIdx.x >> 6;
    int lane = threadIdx.x & 63;
    int row  = blockIdx.x * 4 + wave;
    const float* p = xq + (size_t)row * HH + lane * 8;
    float4 a0 = *(const float4*)(p);
    float4 a1 = *(const float4*)(p + 4);
    float4 b0 = *(const float4*)(w0 + lane * 8);
    float4 b1 = *(const float4*)(w0 + lane * 8 + 4);
    float s = a0.x*b0.x + a0.y*b0.y + a0.z*b0.z + a0.w*b0.w
            + a1.x*b1.x + a1.y*b1.y + a1.z*b1.z + a1.w*b1.w;
    #pragma unroll
    for (int off = 32; off; off >>= 1) s += __shfl_xor(s, off);
    if (lane == 0) sub0[row] = s;
}

// ---------------- K_prep_q: xqw2b[q][h]=bf16(xq*w2); xqmT[h][q]=bf16(xq*qm)
__global__ __launch_bounds__(256) void k_prep_q(const float* __restrict__ xq,
                                                const float* __restrict__ w2,
                                                const float* __restrict__ qmask,
                                                unsigned short* __restrict__ xqw2b,
                                                unsigned short* __restrict__ xqmT) {
    int b  = blockIdx.y;
    int ht = blockIdx.x * 128;
    int tid = threadIdx.x;
    __shared__ __align__(16) unsigned short sT[128][132];

    {
        int q  = tid >> 1;
        int hh = (tid & 1) * 64;
        float qm = qmask[b * QQ + q];
        const float* xp = xq + ((size_t)b * QQ + q) * HH + ht + hh;
        unsigned short* wr = xqw2b + ((size_t)b * QQ + q) * HH + ht + hh;
        #pragma unroll
        for (int i = 0; i < 16; i++) {
            float4 v = *(const float4*)(xp + i * 4);
            float4 w = *(const float4*)(w2 + ht + hh + i * 4);
            uint2 pw; pw.x = pk2(v.x * w.x, v.y * w.y);
                      pw.y = pk2(v.z * w.z, v.w * w.w);
            *(uint2*)(wr + i * 4) = pw;
            uint2 pm; pm.x = pk2(v.x * qm, v.y * qm);
                      pm.y = pk2(v.z * qm, v.w * qm);
            *(uint2*)(&sT[q][hh + i * 4]) = pm;
        }
    }
    __syncthreads();
    {
        int h  = tid >> 1;
        int qh = (tid & 1) * 64;
        unsigned short* orow = xqmT + ((size_t)b * HH + ht + h) * QQ + qh;
        #pragma unroll
        for (int i = 0; i < 8; i++) {
            uint4 o;
            o.x = (unsigned)sT[qh + i*8 + 0][h] | ((unsigned)sT[qh + i*8 + 1][h] << 16);
            o.y = (unsigned)sT[qh + i*8 + 2][h] | ((unsigned)sT[qh + i*8 + 3][h] << 16);
            o.z = (unsigned)sT[qh + i*8 + 4][h] | ((unsigned)sT[qh + i*8 + 5][h] << 16);
            o.w = (unsigned)sT[qh + i*8 + 6][h] | ((unsigned)sT[qh + i*8 + 7][h] << 16);
            *(uint4*)(orow + i * 8) = o;
        }
    }
}

// ---------------- K_prep_c: xcb[c][h] bf16; xcmT[h][c] bf16*cmask; sub1 ---
__global__ __launch_bounds__(256) void k_prep_c(const float* __restrict__ xc,
                                                const float* __restrict__ w1,
                                                const float* __restrict__ cmask,
                                                unsigned short* __restrict__ xcb,
                                                unsigned short* __restrict__ xcmT,
                                                float* __restrict__ sub1) {
    int b  = blockIdx.y;
    int c0 = blockIdx.x * 128;
    int tid = threadIdx.x;
    int lane = tid & 63, w = tid >> 6;
    __shared__ __align__(16) unsigned short sX[32 * 520];   // [c'][h], stride 520
    __shared__ float sW1[512];
    sW1[tid] = w1[tid]; sW1[tid + 256] = w1[tid + 256];
    __syncthreads();

    for (int g = 0; g < 4; g++) {
        // --- phase A: 32 c-rows; coalesced read, xcb write, sub1, LDS fill
        #pragma unroll
        for (int i = 0; i < 8; i++) {
            int rl = i * 4 + w;                 // 0..31 within group
            int c  = c0 + g * 32 + rl;
            const float* xp = xc + ((size_t)b * CC + c) * HH + lane * 8;
            float4 v0 = *(const float4*)xp;
            float4 v1 = *(const float4*)(xp + 4);
            float cm = cmask[b * CC + c];
            const float* wp = sW1 + lane * 8;
            float d = v0.x*wp[0] + v0.y*wp[1] + v0.z*wp[2] + v0.w*wp[3]
                    + v1.x*wp[4] + v1.y*wp[5] + v1.z*wp[6] + v1.w*wp[7];
            #pragma unroll
            for (int off = 32; off; off >>= 1) d += __shfl_xor(d, off);
            if (lane == 0) sub1[(size_t)b * CC + c] = d;
            uint4 p;
            p.x = pk2(v0.x, v0.y); p.y = pk2(v0.z, v0.w);
            p.z = pk2(v1.x, v1.y); p.w = pk2(v1.z, v1.w);
            *(uint4*)(xcb + ((size_t)b * CC + c) * HH + lane * 8) = p;
            uint4 m;
            m.x = pk2(v0.x * cm, v0.y * cm); m.y = pk2(v0.z * cm, v0.w * cm);
            m.z = pk2(v1.x * cm, v1.y * cm); m.w = pk2(v1.z * cm, v1.w * cm);
            *(uint4*)(sX + rl * 520 + lane * 8) = m;
        }
        __syncthreads();
        // --- phase B: transpose out; thread handles h = 2*tid, 2*tid+1
        {
            unsigned wlo[16], whi[16];
            #pragma unroll
            for (int j = 0; j < 16; j++) {
                unsigned u0 = *(const unsigned*)(sX + (2*j)     * 520 + 2 * tid);
                unsigned u1 = *(const unsigned*)(sX + (2*j + 1) * 520 + 2 * tid);
                wlo[j] = (u0 & 0xFFFFu) | (u1 << 16);
                whi[j] = (u0 >> 16)     | (u1 & 0xFFFF0000u);
            }
            unsigned short* o0 = xcmT + ((size_t)b * HH + 2 * tid) * CC + c0 + g * 32;
            unsigned short* o1 = o0 + CC;
            #pragma unroll
            for (int j = 0; j < 4; j++) {
                *(uint4*)(o0 + j * 8) = *(uint4*)(wlo + j * 4);
                *(uint4*)(o1 + j * 8) = *(uint4*)(whi + j * 4);
            }
        }
        __syncthreads();
    }
}

// ---------------- K1: S = xcb · xqw2b^T (pure GLD16 GEMM) -> E, E^T, sums -
__global__ __launch_bounds__(256) void k_scores(
    const unsigned short* __restrict__ xcb, const unsigned short* __restrict__ xqw2b,
    const float* __restrict__ cmask, const float* __restrict__ qmask,
    const float* __restrict__ bias, const float* __restrict__ sub0,
    const float* __restrict__ sub1, unsigned short* __restrict__ Ebf,
    unsigned short* __restrict__ EbfT, float* __restrict__ rowsum,
    float* __restrict__ colsum) {
    int b  = blockIdx.y;
    int c0 = blockIdx.x * 128;
    int tid  = threadIdx.x;
    int lane = tid & 63, wave = tid >> 6;
    int quad = lane >> 4, lcol = lane & 15;
    int wrow = (wave >> 1) * 64, wcol = (wave & 1) * 64;

    __shared__ __align__(16) unsigned short sA[128 * 32];  // [c][k]
    __shared__ __align__(16) unsigned short sB[128 * 32];  // [q][k]
    __shared__ float sS1[128], sS0[128], sQm[128], sCm[128];
    __shared__ float sRowP[2][128], sColP[2][128];

    if (tid < 128) {
        sS1[tid] = sub1[(size_t)b * CC + c0 + tid];
        sS0[tid] = sub0[b * QQ + tid] + bias[0];
        sQm[tid] = qmask[b * QQ + tid];
        sCm[tid] = cmask[b * CC + c0 + tid];
    }

    f32x4 acc[4][4];
    #pragma unroll
    for (int i = 0; i < 4; i++)
        #pragma unroll
        for (int j = 0; j < 4; j++) acc[i][j] = (f32x4)0.0f;

    for (int k0 = 0; k0 < HH; k0 += 32) {
        __syncthreads();
        #pragma unroll
        for (int j = 0; j < 2; j++) {
            int chunk = wave * 2 + j;
            int row = chunk * 16 + (lane >> 2);
            int kb  = (lane & 3) * 8;
            GLD16(xcb   + ((size_t)(b * CC + c0 + row)) * HH + k0 + kb,
                  sA + chunk * 512);
            GLD16(xqw2b + ((size_t)(b * QQ + row)) * HH + k0 + kb,
                  sB + chunk * 512);
        }
        __syncthreads();
        bf16x8 af[4];
        #pragma unroll
        for (int mi = 0; mi < 4; mi++)
            af[mi] = *(const bf16x8*)(sA + (wrow + mi * 16 + lcol) * 32 + quad * 8);
        #pragma unroll
        for (int ni = 0; ni < 4; ni++) {
            bf16x8 bfr = *(const bf16x8*)(sB + (wcol + ni * 16 + lcol) * 32 + quad * 8);
            #pragma unroll
            for (int mi = 0; mi < 4; mi++)
                acc[mi][ni] = __builtin_amdgcn_mfma_f32_16x16x32_bf16(
                    af[mi], bfr, acc[mi][ni], 0, 0, 0);
        }
    }

    // epilogue: E = exp(S), rowsum/colsum partials, E + E^T stores
    float rsp[4][4];
    float csp[4] = {0.f, 0.f, 0.f, 0.f};
    #pragma unroll
    for (int mi = 0; mi < 4; mi++)
        #pragma unroll
        for (int r = 0; r < 4; r++) rsp[mi][r] = 0.f;

    #pragma unroll
    for (int mi = 0; mi < 4; mi++) {
        int rb = wrow + mi * 16 + quad * 4;
        #pragma unroll
        for (int ni = 0; ni < 4; ni++) {
            int col = wcol + ni * 16 + lcol;
            float qm = sQm[col], s0 = sS0[col];
            float ev[4];
            #pragma unroll
            for (int r = 0; r < 4; r++) {
                int row = rb + r;
                float e = __expf(acc[mi][ni][r] + sS1[row] + s0);
                ev[r] = e;
                rsp[mi][r] += e * qm;
                csp[ni] += e * sCm[row];
                Ebf[((size_t)(b * CC + c0 + row)) * QQ + col] = f2bf(e);
            }
            uint2 o;
            o.x = pk2(ev[0], ev[1]);
            o.y = pk2(ev[2], ev[3]);
            *(uint2*)(EbfT + ((size_t)(b * QQ + col)) * CC + c0 + rb) = o;
        }
    }
    #pragma unroll
    for (int mi = 0; mi < 4; mi++)
        #pragma unroll
        for (int r = 0; r < 4; r++) {
            float v = rsp[mi][r];
            v += __shfl_xor(v, 1); v += __shfl_xor(v, 2);
            v += __shfl_xor(v, 4); v += __shfl_xor(v, 8);
            if (lcol == 0) sRowP[wave & 1][wrow + mi * 16 + quad * 4 + r] = v;
        }
    #pragma unroll
    for (int ni = 0; ni < 4; ni++) {
        float v = csp[ni];
        v += __shfl_xor(v, 16); v += __shfl_xor(v, 32);
        if (quad == 0) sColP[wave >> 1][wcol + ni * 16 + lcol] = v;
    }
    __syncthreads();
    if (tid < 128) {
        rowsum[(size_t)b * CC + c0 + tid] = sRowP[0][tid] + sRowP[1][tid];
        atomicAdd(&colsum[b * QQ + tid], sColP[0][tid] + sColP[1][tid]);
    }
}

// ---------------- K2: tmpT[h][q] = (qm/colsum)[q] * sum_c xcmT[h][c]*E^T[q][c]
__global__ __launch_bounds__(256) void k_tmp(
    const unsigned short* __restrict__ xcmT, const unsigned short* __restrict__ EbfT,
    const float* __restrict__ qmask, const float* __restrict__ colsum,
    unsigned short* __restrict__ tmpT) {
    int b  = blockIdx.y;
    int h0 = blockIdx.x * 128;
    int tid  = threadIdx.x;
    int lane = tid & 63, wave = tid >> 6;
    int quad = lane >> 4, lcol = lane & 15;
    int wrow = (wave >> 1) * 64, wcol = (wave & 1) * 64;

    __shared__ __align__(16) unsigned short sA[128 * 32];  // [h][c-chunk]
    __shared__ __align__(16) unsigned short sB[128 * 32];  // [q][c-chunk]
    __shared__ float sInv[128];
    if (tid < 128) sInv[tid] = qmask[b * QQ + tid] / colsum[b * QQ + tid];

    f32x4 acc[4][4];
    #pragma unroll
    for (int i = 0; i < 4; i++)
        #pragma unroll
        for (int j = 0; j < 4; j++) acc[i][j] = (f32x4)0.0f;

    for (int c0k = 0; c0k < CC; c0k += 32) {
        __syncthreads();
        #pragma unroll
        for (int j = 0; j < 2; j++) {
            int chunk = wave * 2 + j;
            int row = chunk * 16 + (lane >> 2);
            int kb  = (lane & 3) * 8;
            GLD16(xcmT + ((size_t)(b * HH + h0 + row)) * CC + c0k + kb,
                  sA + chunk * 512);
            GLD16(EbfT + ((size_t)(b * QQ + row)) * CC + c0k + kb,
                  sB + chunk * 512);
        }
        __syncthreads();
        bf16x8 af[4];
        #pragma unroll
        for (int mi = 0; mi < 4; mi++)
            af[mi] = *(const bf16x8*)(sA + (wrow + mi * 16 + lcol) * 32 + quad * 8);
        #pragma unroll
        for (int ni = 0; ni < 4; ni++) {
            bf16x8 bfr = *(const bf16x8*)(sB + (wcol + ni * 16 + lcol) * 32 + quad * 8);
            #pragma unroll
            for (int mi = 0; mi < 4; mi++)
                acc[mi][ni] = __builtin_amdgcn_mfma_f32_16x16x32_bf16(
                    af[mi], bfr, acc[mi][ni], 0, 0, 0);
        }
    }
    #pragma unroll
    for (int mi = 0; mi < 4; mi++) {
        int hb = wrow + mi * 16 + quad * 4;
        #pragma unroll
        for (int ni = 0; ni < 4; ni++) {
            int q = wcol + ni * 16 + lcol;
            float iv = sInv[q];
            #pragma unroll
            for (int r = 0; r < 4; r++)
                tmpT[((size_t)(b * HH + h0 + hb + r)) * QQ + q] =
                    f2bf(acc[mi][ni][r] * iv);
        }
    }
}

// ---------------- K3: c2q = (E/rowsum)·xqm ; q2c = (E/rowsum)·tmpT^T -------
__global__ __launch_bounds__(256) void k_out(
    const unsigned short* __restrict__ Ebf, const unsigned short* __restrict__ xqmT,
    const unsigned short* __restrict__ tmpT, const float* __restrict__ rowsum,
    float* __restrict__ c2q, float* __restrict__ q2c) {
    int b  = blockIdx.z;
    int c0 = blockIdx.y * 128;
    int h0 = blockIdx.x * 128;
    int tid  = threadIdx.x;
    int lane = tid & 63, wave = tid >> 6;
    int quad = lane >> 4, lcol = lane & 15;
    int wrow = (wave >> 1) * 64, wcol = (wave & 1) * 64;

    __shared__ __align__(16) unsigned short sA[128 * 32];
    __shared__ __align__(16) unsigned short sB1[128 * 32];
    __shared__ __align__(16) unsigned short sB2[128 * 32];
    __shared__ float sInvR[128];
    if (tid < 128) sInvR[tid] = 1.0f / rowsum[(size_t)b * CC + c0 + tid];

    f32x4 acc1[4][4], acc2[4][4];
    #pragma unroll
    for (int i = 0; i < 4; i++)
        #pragma unroll
        for (int j = 0; j < 4; j++) { acc1[i][j] = (f32x4)0.f; acc2[i][j] = (f32x4)0.f; }

    for (int k0 = 0; k0 < QQ; k0 += 32) {
        __syncthreads();
        #pragma unroll
        for (int j = 0; j < 2; j++) {
            int chunk = wave * 2 + j;
            int row = chunk * 16 + (lane >> 2);
            int kb  = (lane & 3) * 8;
            GLD16(Ebf  + ((size_t)(b * CC + c0 + row)) * QQ + k0 + kb,
                  sA + chunk * 512);
            GLD16(xqmT + ((size_t)(b * HH + h0 + row)) * QQ + k0 + kb,
                  sB1 + chunk * 512);
            GLD16(tmpT + ((size_t)(b * HH + h0 + row)) * QQ + k0 + kb,
                  sB2 + chunk * 512);
        }
        __syncthreads();
        bf16x8 af[4];
        #pragma unroll
        for (int mi = 0; mi < 4; mi++)
            af[mi] = *(const bf16x8*)(sA + (wrow + mi * 16 + lcol) * 32 + quad * 8);
        #pragma unroll
        for (int ni = 0; ni < 4; ni++) {
            bf16x8 b1 = *(const bf16x8*)(sB1 + (wcol + ni * 16 + lcol) * 32 + quad * 8);
            bf16x8 b2 = *(const bf16x8*)(sB2 + (wcol + ni * 16 + lcol) * 32 + quad * 8);
            #pragma unroll
            for (int mi = 0; mi < 4; mi++) {
                acc1[mi][ni] = __builtin_amdgcn_mfma_f32_16x16x32_bf16(
                    af[mi], b1, acc1[mi][ni], 0, 0, 0);
                acc2[mi][ni] = __builtin_amdgcn_mfma_f32_16x16x32_bf16(
                    af[mi], b2, acc2[mi][ni], 0, 0, 0);
            }
        }
    }
    #pragma unroll
    for (int mi = 0; mi < 4; mi++) {
        int rb = wrow + mi * 16 + quad * 4;
        float ir0 = sInvR[rb], ir1 = sInvR[rb + 1], ir2 = sInvR[rb + 2], ir3 = sInvR[rb + 3];
        #pragma unroll
        for (int ni = 0; ni < 4; ni++) {
            int col = h0 + wcol + ni * 16 + lcol;
            size_t o0 = ((size_t)(b * CC + c0 + rb)) * HH + col;
            c2q[o0]        = acc1[mi][ni][0] * ir0;
            c2q[o0 + HH]   = acc1[mi][ni][1] * ir1;
            c2q[o0 + 2*HH] = acc1[mi][ni][2] * ir2;
            c2q[o0 + 3*HH] = acc1[mi][ni][3] * ir3;
            q2c[o0]        = acc2[mi][ni][0] * ir0;
            q2c[o0 + HH]   = acc2[mi][ni][1] * ir1;
            q2c[o0 + 2*HH] = acc2[mi][ni][2] * ir2;
            q2c[o0 + 3*HH] = acc2[mi][ni][3] * ir3;
        }
    }
}

extern "C" void kernel_launch(void* const* d_in, const int* in_sizes, int n_in,
                              void* d_out, int out_size, void* d_ws, size_t ws_size,
                              hipStream_t stream) {
    const float* xc    = (const float*)d_in[0];
    const float* xq    = (const float*)d_in[1];
    const float* cmask = (const float*)d_in[2];
    const float* qmask = (const float*)d_in[3];
    const float* w0    = (const float*)d_in[4];
    const float* w1    = (const float*)d_in[5];
    const float* w2    = (const float*)d_in[6];
    const float* bias  = (const float*)d_in[7];

    float* out = (float*)d_out;
    float* c2q = out;
    float* q2c = out + (size_t)BB * CC * HH;

    unsigned short* Ebf   = (unsigned short*)d_ws;            // BB*CC*QQ
    unsigned short* EbfT  = Ebf   + (size_t)BB * CC * QQ;     // BB*QQ*CC
    unsigned short* xqw2b = EbfT  + (size_t)BB * QQ * CC;     // BB*QQ*HH
    unsigned short* xqmT  = xqw2b + (size_t)BB * QQ * HH;     // BB*HH*QQ
    unsigned short* tmpT  = xqmT  + (size_t)BB * QQ * HH;     // BB*HH*QQ
    unsigned short* xcb   = tmpT  + (size_t)BB * HH * QQ;     // BB*CC*HH
    unsigned short* xcmT  = xcb   + (size_t)BB * CC * HH;     // BB*HH*CC
    float* rowsum = (float*)(xcmT + (size_t)BB * HH * CC);    // BB*CC
    float* colsum = rowsum + (size_t)BB * CC;                 // BB*QQ
    float* sub0   = colsum + (size_t)BB * QQ;                 // BB*QQ
    float* sub1   = sub0   + (size_t)BB * QQ;                 // BB*CC

    k_sub0  <<<dim3(BB * QQ / 4),        256, 0, stream>>>(xq, w0, sub0, colsum);
    k_prep_q<<<dim3(HH / 128, BB),       256, 0, stream>>>(xq, w2, qmask, xqw2b, xqmT);
    k_prep_c<<<dim3(CC / 128, BB),       256, 0, stream>>>(xc, w1, cmask, xcb, xcmT, sub1);
    k_scores<<<dim3(CC / 128, BB),       256, 0, stream>>>(xcb, xqw2b, cmask, qmask,
                                                           bias, sub0, sub1,
                                                           Ebf, EbfT, rowsum, colsum);
    k_tmp   <<<dim3(HH / 128, BB),       256, 0, stream>>>(xcmT, EbfT, qmask,
                                                           colsum, tmpT);
    k_out   <<<dim3(HH / 128, CC / 128, BB), 256, 0, stream>>>(Ebf, xqmT, tmpT,
                                                               rowsum, c2q, q2c);
}